// Round 1
// baseline (4845.328 us; speedup 1.0000x reference)
//
#include <hip/hip_runtime.h>

typedef unsigned short u16;
typedef unsigned int u32;
typedef unsigned long long u64;
typedef __attribute__((ext_vector_type(8))) short bf16x8;
typedef __attribute__((ext_vector_type(4))) float f32x4;
typedef __attribute__((ext_vector_type(8))) unsigned short u16x8;
typedef __attribute__((ext_vector_type(4))) unsigned short u16x4;

#define MFMA16(a, b, c) __builtin_amdgcn_mfma_f32_16x16x32_bf16(a, b, c, 0, 0, 0)

__device__ __forceinline__ u16 f2b(float f) {
    u32 u = __builtin_bit_cast(u32, f);
    u32 r = (u + 0x7fffu + ((u >> 16) & 1u)) >> 16;
    return (u16)r;
}
__device__ __forceinline__ float b2f(u16 h) {
    u32 u = ((u32)h) << 16;
    return __builtin_bit_cast(float, u);
}
__device__ __forceinline__ float sigm(float x) { return 1.0f / (1.0f + __expf(-x)); }
__device__ __forceinline__ float tanh_fast(float x) { return 1.0f - 2.0f / (__expf(2.0f * x) + 1.0f); }

// Cross-XCD-coherent accesses WITHOUT fences: agent-scope relaxed atomics
// lower to sc1 (MALL-coherent) global accesses. Used ONLY for the h exchange
// and flags -- everything consumed by a LATER DISPATCH (out1/out2) uses plain
// cached stores (kernel-boundary coherence), keeping the MALL path clear for
// the latency-critical flag/h round trip.
__device__ __forceinline__ u64 aload64(const void* p) {
    return __hip_atomic_load((const u64*)p, __ATOMIC_RELAXED, __HIP_MEMORY_SCOPE_AGENT);
}
__device__ __forceinline__ u32 aload32(const void* p) {
    return __hip_atomic_load((const u32*)p, __ATOMIC_RELAXED, __HIP_MEMORY_SCOPE_AGENT);
}
__device__ __forceinline__ void astore32(void* p, u32 v) {
    __hip_atomic_store((u32*)p, v, __ATOMIC_RELAXED, __HIP_MEMORY_SCOPE_AGENT);
}
__device__ __forceinline__ void astore64(void* p, u64 v) {
    __hip_atomic_store((u64*)p, v, __ATOMIC_RELAXED, __HIP_MEMORY_SCOPE_AGENT);
}

// ---------------------------------------------------------------------------
// Embedding gather + f32->bf16 cast, time-major output x[t*64+b][e]
__global__ __launch_bounds__(256) void embed_k(const int* __restrict__ enc,
                                               const float* __restrict__ emb,
                                               u16* __restrict__ xb) {
    int idx = (blockIdx.x * 256 + threadIdx.x) * 4;
    int row = idx >> 9;
    int e = idx & 511;
    int t = row >> 6, b = row & 63;
    int tok = enc[b * 256 + t];
    const float4 v = *(const float4*)(emb + (size_t)tok * 512 + e);
    u16x4 o;
    o.x = f2b(v.x); o.y = f2b(v.y); o.z = f2b(v.z); o.w = f2b(v.w);
    *(u16x4*)(xb + idx) = o;
}

// Mask words: maskw[t] bit b = (enc[b][t] != 0)
__global__ void mask_k(const int* __restrict__ enc, u64* __restrict__ mw) {
    int t = threadIdx.x;
    u64 m = 0;
#pragma unroll 8
    for (int b = 0; b < 64; ++b)
        if (enc[b * 256 + t] != 0) m |= (1ull << b);
    mw[t] = m;
}

// ---------------------------------------------------------------------------
// Cast f32 [K][N] -> bf16 transposed [N][K] via LDS tile
__global__ __launch_bounds__(256) void castT_k(const float* __restrict__ src,
                                               u16* __restrict__ dst, int K, int N) {
    __shared__ float tile[64][65];
    int n0 = blockIdx.x * 64, k0 = blockIdx.y * 64;
    int tid = threadIdx.x;
#pragma unroll
    for (int it = 0; it < 4; ++it) {
        int e = tid + it * 256;
        int kk = e >> 4;
        int nn = (e & 15) * 4;
        const float4 v = *(const float4*)(src + (size_t)(k0 + kk) * N + n0 + nn);
        tile[kk][nn] = v.x; tile[kk][nn + 1] = v.y;
        tile[kk][nn + 2] = v.z; tile[kk][nn + 3] = v.w;
    }
    __syncthreads();
#pragma unroll
    for (int it = 0; it < 2; ++it) {
        int e = tid + it * 256;
        int nn = e >> 3;
        int ks = (e & 7) * 8;
        u16x8 o;
#pragma unroll
        for (int j = 0; j < 8; ++j) o[j] = f2b(tile[ks + j][nn]);
        *(u16x8*)(dst + (size_t)(n0 + nn) * K + k0 + ks) = o;
    }
}

// ---------------------------------------------------------------------------
// bf16 MFMA GEMM: zxT[dir][t][col][b] = (A[16384][Ak] @ Bt[dir]^T + bias[dir]),
// output TRANSPOSED per timestep for the recurrence's vectorized reads.
__global__ __launch_bounds__(256) void gemm_bias_k(
    const u16* __restrict__ A, int Ak,
    const u16* __restrict__ BtF, const u16* __restrict__ BtB,
    const float* __restrict__ biasF, const float* __restrict__ biasB,
    u16* __restrict__ outF, u16* __restrict__ outB) {
    const int dir = blockIdx.z;
    const u16* __restrict__ Bt = dir ? BtB : BtF;
    const float* __restrict__ bias = dir ? biasB : biasF;
    u16* __restrict__ out = dir ? outB : outF;

    const int m0 = blockIdx.y * 128, n0 = blockIdx.x * 128;
    __shared__ __align__(16) u16 As[128 * 40];
    __shared__ __align__(16) u16 Bs[128 * 40];
    const int tid = threadIdx.x;
    const int lane = tid & 63, w = tid >> 6;
    const int l15 = lane & 15, quad = lane >> 4;
    const int rb = (w >> 1) * 64, cb = (w & 1) * 64;

    f32x4 acc[4][4];
#pragma unroll
    for (int i = 0; i < 4; ++i)
#pragma unroll
        for (int j = 0; j < 4; ++j) acc[i][j] = (f32x4){0.f, 0.f, 0.f, 0.f};

    const int nkt = Ak >> 5;
    for (int kt = 0; kt < nkt; ++kt) {
        __syncthreads();
#pragma unroll
        for (int it = 0; it < 2; ++it) {
            int s = tid + it * 256;
            int r = s >> 2, seg = s & 3;
            *(uint4*)&As[r * 40 + seg * 8] =
                *(const uint4*)&A[(size_t)(m0 + r) * Ak + kt * 32 + seg * 8];
            *(uint4*)&Bs[r * 40 + seg * 8] =
                *(const uint4*)&Bt[(size_t)(n0 + r) * Ak + kt * 32 + seg * 8];
        }
        __syncthreads();
        bf16x8 af[4], bfr[4];
#pragma unroll
        for (int i = 0; i < 4; ++i)
            af[i] = *(const bf16x8*)&As[(rb + i * 16 + l15) * 40 + quad * 8];
#pragma unroll
        for (int j = 0; j < 4; ++j)
            bfr[j] = *(const bf16x8*)&Bs[(cb + j * 16 + l15) * 40 + quad * 8];
#pragma unroll
        for (int i = 0; i < 4; ++i)
#pragma unroll
            for (int j = 0; j < 4; ++j) acc[i][j] = MFMA16(af[i], bfr[j], acc[i][j]);
    }
    // epilogue: add bias, store bf16 transposed: zxT[(t*2048 + col)*64 + b]
    // rows m..m+3 share t because m === 0 (mod 4) and 64 | t-boundary.
#pragma unroll
    for (int j = 0; j < 4; ++j) {
        int col = n0 + cb + j * 16 + l15;
        float bv = bias[col];
#pragma unroll
        for (int i = 0; i < 4; ++i) {
            int m = m0 + rb + i * 16 + quad * 4;
            int t = m >> 6, b0 = m & 63;
            u16x4 o;
#pragma unroll
            for (int r = 0; r < 4; ++r) o[r] = f2b(acc[i][j][r] + bv);
            *(u16x4*)&out[((size_t)t * 2048 + col) * 64 + b0] = o;
        }
    }
}

// ---------------------------------------------------------------------------
// Persistent bidirectional LSTM recurrence, fence-free, PER-WAVE decoupled.
// 128 WGs: 0..63 fwd, 64..127 bwd. Each WG owns 8 units (32 gate-cols) with
// U-slices resident in registers. Each of the 4 waves owns 16 batch rows and
// forms an INDEPENDENT recurrence chain: wave w only reads/writes hbuf rows
// w*16..w*16+15, so it gates only on wave-w flags of the other WGs. No
// __syncthreads in the step loop at all.
// Publish protocol per wave per step: h stores (sc1, 8B) -> asm vmcnt(0)
// drain ("memory" clobber orders the relaxed flag store after it) -> lane 0
// stores flg[w*64 + wgu] = s+1. Consumer wave w spin-polls flg[w*64 + lane].
// Outputs out1/out2 are PLAIN cached stores (consumed by later dispatches;
// kernel-boundary coherence) so they stay off the MALL critical path.
__global__ __launch_bounds__(256, 1) void lstm_rec_k(
    const u16* __restrict__ zxF, const u16* __restrict__ zxB,  // [256][2048][64]
    const u16* __restrict__ UtF, const u16* __restrict__ UtB,  // [2048][512]
    const u64* __restrict__ maskw,
    u16* __restrict__ hbufF, u16* __restrict__ hbufB,          // each 2*[64*512]
    u32* __restrict__ flgF, u32* __restrict__ flgB,            // each [4][64]
    u16* __restrict__ out1,    // layer 1: [256][64][1024] bf16
    float* __restrict__ out2,  // layer 2: d_out
    int layer) {
    const int wg = blockIdx.x;
    const int dir = wg >> 6;
    const int wgu = wg & 63;
    const u16* __restrict__ zx = dir ? zxB : zxF;
    const u16* __restrict__ Ut = dir ? UtB : UtF;
    u16* __restrict__ hbuf = dir ? hbufB : hbufF;
    u32* __restrict__ flg = dir ? flgB : flgF;

    const int tid = threadIdx.x;
    const int lane = tid & 63, w = tid >> 6;
    const int l15 = lane & 15, quad = lane >> 4;
    const bool hi = (lane & 8) != 0;
    const int gc_l = (l15 >> 3) * 512 + wgu * 8 + (l15 & 7);
    const int u = wgu * 8 + (lane & 7);
    const int brow = w * 16 + l15;
    const int b0 = w * 16 + quad * 4;  // batch base for acc rows

    u32* __restrict__ flgw = flg + w * 64;  // this wave's flag row

    // Preload U fragments: 2 N-tiles x 16 K-chunks (VGPR/AGPR-resident)
    bf16x8 bfr[2][16];
#pragma unroll
    for (int nt = 0; nt < 2; ++nt)
#pragma unroll
        for (int kt = 0; kt < 16; ++kt)
            bfr[nt][kt] = *(const bf16x8*)&Ut[(size_t)(nt * 1024 + gc_l) * 512 + kt * 32 + quad * 8];

    float hreg[4] = {0.f, 0.f, 0.f, 0.f};
    float creg[4] = {0.f, 0.f, 0.f, 0.f};

    // initial zx prefetch (t of step 0)
    int t0 = dir ? 255 : 0;
    u16x4 pz0 = *(const u16x4*)&zx[((size_t)t0 * 2048 + gc_l) * 64 + b0];
    u16x4 pz1 = *(const u16x4*)&zx[((size_t)t0 * 2048 + 1024 + gc_l) * 64 + b0];

    union HU { u64 q[2]; bf16x8 v; };

    for (int s = 0; s < 256; ++s) {
        const int t = dir ? (255 - s) : s;

        // gate: wait until all 64 WGs' wave-w published step s (i.e. finished
        // step s-1 for rows w*16.. including their h reads -> WAR-safe).
        if (s) {
            u32 v = aload32(&flgw[lane]);
            while (__ballot(v < (u32)s)) v = aload32(&flgw[lane]);
        }

        const u64 mw = maskw[t];  // hot 2KB table, hoisted early for slack

        // h[s] slot: sc1 loads from MALL
        const u16* hbase = hbuf + (s & 1) * 32768 + brow * 512 + quad * 8;
        bf16x8 hfr[16];
#pragma unroll
        for (int kt = 0; kt < 16; ++kt) {
            HU hu;
            hu.q[0] = aload64(hbase + kt * 32);
            hu.q[1] = aload64(hbase + kt * 32 + 4);
            hfr[kt] = hu.v;
        }

        f32x4 acc0, acc1;
#pragma unroll
        for (int r = 0; r < 4; ++r) { acc0[r] = b2f(pz0[r]); acc1[r] = b2f(pz1[r]); }
#pragma unroll
        for (int kt = 0; kt < 16; ++kt) {
            acc0 = MFMA16(hfr[kt], bfr[0][kt], acc0);
            acc1 = MFMA16(hfr[kt], bfr[1][kt], acc1);
        }

        u16* __restrict__ hn = hbuf + ((s + 1) & 1) * 32768;
        u64 qs[4];
#pragma unroll
        for (int r = 0; r < 4; ++r) {
            int b = b0 + r;
            float z0 = acc0[r], z1 = acc1[r];
            float p0 = __shfl_xor(z0, 8);
            float p1 = __shfl_xor(z1, 8);
            float iz = hi ? p0 : z0, fz = hi ? z0 : p0;
            float gz = hi ? p1 : z1, oz = hi ? z1 : p1;
            float i_ = sigm(iz), f_ = sigm(fz), g_ = tanh_fast(gz), o_ = sigm(oz);
            float cn = f_ * creg[r] + i_ * g_;
            float hv = o_ * tanh_fast(cn);
            if (!((mw >> b) & 1ull)) { cn = creg[r]; hv = hreg[r]; }
            creg[r] = cn; hreg[r] = hv;
            if (!hi) {
                u16 hb = f2b(hv);
                // pack (u..u+3) into u64; lane&3==0 stores 8B (u === 0 mod 4)
                u32 pair = (u32)hb | (((u32)(u16)__shfl_xor((int)(u32)hb, 1)) << 16);
                u64 q = (u64)pair | ((u64)(u32)__shfl_xor((int)pair, 2) << 32);
                qs[r] = q;
                if (!(lane & 3)) astore64(&hn[b * 512 + u], q);
            }
        }

        // drain THIS WAVE's h stores, then publish (asm memory clobber keeps
        // the relaxed flag store ordered after the drain at compile time;
        // in-order per-wave VMEM issue + vmcnt(0) orders it in hardware).
        asm volatile("s_waitcnt vmcnt(0)" ::: "memory");
        if (lane == 0) astore32(&flgw[wgu], (u32)(s + 1));

        // post-publish: output stores (PLAIN, cached, coalesced 8B) + next-step
        // zx prefetch overlap the next gate's poll.
        if (!hi) {
            if (layer == 1) {
                if (!(lane & 3)) {
#pragma unroll
                    for (int r = 0; r < 4; ++r)
                        *(u64*)&out1[((size_t)t * 64 + (b0 + r)) * 1024 + dir * 512 + u] = qs[r];
                }
            } else {
#pragma unroll
                for (int r = 0; r < 4; ++r) {
                    u32 h32 = __builtin_bit_cast(u32, hreg[r]);
                    u32 ot = (u32)__shfl_xor((int)h32, 1);
                    if (!(lane & 1)) {
                        u64 qq = (u64)h32 | ((u64)ot << 32);
                        *(u64*)&out2[(size_t)(b0 + r) * 262144 + (size_t)t * 1024 + dir * 512 + u] = qq;
                    }
                }
            }
        }
        if (layer == 2 && s == 255 && !hi) {
#pragma unroll
            for (int r = 0; r < 4; ++r) {
                int b = b0 + r;
                out2[16777216 + b * 1024 + dir * 512 + u] = hreg[r];
                out2[16777216 + 65536 + b * 1024 + dir * 512 + u] = creg[r];
            }
        }
        {
            int tn = dir ? (s < 255 ? 254 - s : 0) : (s < 255 ? s + 1 : 255);
            pz0 = *(const u16x4*)&zx[((size_t)tn * 2048 + gc_l) * 64 + b0];
            pz1 = *(const u16x4*)&zx[((size_t)tn * 2048 + 1024 + gc_l) * 64 + b0];
        }
    }
}

// ---------------------------------------------------------------------------
extern "C" void kernel_launch(void* const* d_in, const int* in_sizes, int n_in,
                              void* d_out, int out_size, void* d_ws, size_t ws_size,
                              hipStream_t stream) {
    const int* enc = (const int*)d_in[0];
    const float* emb = (const float*)d_in[1];
    const float* W1f = (const float*)d_in[2];
    const float* U1f = (const float*)d_in[3];
    const float* b1f = (const float*)d_in[4];
    const float* W1b = (const float*)d_in[5];
    const float* U1b = (const float*)d_in[6];
    const float* b1b = (const float*)d_in[7];
    const float* W2f = (const float*)d_in[8];
    const float* U2f = (const float*)d_in[9];
    const float* b2f = (const float*)d_in[10];
    const float* W2b = (const float*)d_in[11];
    const float* U2b = (const float*)d_in[12];
    const float* b2b = (const float*)d_in[13];

    char* ws = (char*)d_ws;
    constexpr size_t ZXF = 0;                      // 67,108,864  bf16 [256][2048][64]
    constexpr size_t ZXB = 67108864;               // 67,108,864
    constexpr size_t XB = 134217728;               // 16,777,216  bf16 [16384][512]
    constexpr size_t OUT1 = 150994944;             // 33,554,432  bf16 [16384][1024]
    constexpr size_t WT = 184549376;               // 20,971,520 packed bf16 transposed weights
    constexpr size_t W1FT = WT + 0;
    constexpr size_t W1BT = WT + 2097152;
    constexpr size_t U1FT = WT + 4194304;
    constexpr size_t U1BT = WT + 6291456;
    constexpr size_t W2FT = WT + 8388608;
    constexpr size_t W2BT = WT + 12582912;
    constexpr size_t U2FT = WT + 16777216;
    constexpr size_t U2BT = WT + 18874368;
    constexpr size_t HBUF = 205520896;             // 262,144: [dir][2][64*512] bf16 (reused per layer)
    constexpr size_t FLG = HBUF + 262144;          // 2 dirs x 4 waves x 64 u32 = 2048 B
    constexpr size_t MASKW = FLG + 2048;           // 2048 bytes

    u16* zxF = (u16*)(ws + ZXF);
    u16* zxB = (u16*)(ws + ZXB);
    u16* xb = (u16*)(ws + XB);
    u16* out1 = (u16*)(ws + OUT1);
    u32* flgs = (u32*)(ws + FLG);
    u64* maskw = (u64*)(ws + MASKW);

    // zero h init buffers + flags (ws is poisoned 0xAA each launch)
    hipMemsetAsync(ws + HBUF, 0, 262144 + 2048, stream);

    embed_k<<<8192, 256, 0, stream>>>(enc, emb, xb);
    mask_k<<<1, 256, 0, stream>>>(enc, maskw);

    castT_k<<<dim3(32, 8), 256, 0, stream>>>(W1f, (u16*)(ws + W1FT), 512, 2048);
    castT_k<<<dim3(32, 8), 256, 0, stream>>>(W1b, (u16*)(ws + W1BT), 512, 2048);
    castT_k<<<dim3(32, 8), 256, 0, stream>>>(U1f, (u16*)(ws + U1FT), 512, 2048);
    castT_k<<<dim3(32, 8), 256, 0, stream>>>(U1b, (u16*)(ws + U1BT), 512, 2048);
    castT_k<<<dim3(32, 16), 256, 0, stream>>>(W2f, (u16*)(ws + W2FT), 1024, 2048);
    castT_k<<<dim3(32, 16), 256, 0, stream>>>(W2b, (u16*)(ws + W2BT), 1024, 2048);
    castT_k<<<dim3(32, 8), 256, 0, stream>>>(U2f, (u16*)(ws + U2FT), 512, 2048);
    castT_k<<<dim3(32, 8), 256, 0, stream>>>(U2b, (u16*)(ws + U2BT), 512, 2048);

    gemm_bias_k<<<dim3(16, 128, 2), 256, 0, stream>>>(
        xb, 512, (u16*)(ws + W1FT), (u16*)(ws + W1BT), b1f, b1b, zxF, zxB);
    lstm_rec_k<<<128, 256, 0, stream>>>(
        zxF, zxB, (u16*)(ws + U1FT), (u16*)(ws + U1BT), maskw,
        (u16*)(ws + HBUF), (u16*)(ws + HBUF + 131072),
        &flgs[0], &flgs[256], out1, nullptr, 1);

    gemm_bias_k<<<dim3(16, 128, 2), 256, 0, stream>>>(
        out1, 1024, (u16*)(ws + W2FT), (u16*)(ws + W2BT), b2f, b2b, zxF, zxB);
    // re-zero h buffers + flags for layer 2 (stream-ordered after lstm1/gemm2)
    hipMemsetAsync(ws + HBUF, 0, 262144 + 2048, stream);
    lstm_rec_k<<<128, 256, 0, stream>>>(
        zxF, zxB, (u16*)(ws + U2FT), (u16*)(ws + U2BT), maskw,
        (u16*)(ws + HBUF), (u16*)(ws + HBUF + 131072),
        &flgs[0], &flgs[256], nullptr, (float*)d_out, 2);
}

// Round 2
// 3122.013 us; speedup vs baseline: 1.5520x; 1.5520x over previous
//
#include <hip/hip_runtime.h>

typedef unsigned short u16;
typedef unsigned int u32;
typedef unsigned long long u64;
typedef __attribute__((ext_vector_type(8))) short bf16x8;
typedef __attribute__((ext_vector_type(4))) float f32x4;
typedef __attribute__((ext_vector_type(8))) unsigned short u16x8;
typedef __attribute__((ext_vector_type(4))) unsigned short u16x4;

#define MFMA16(a, b, c) __builtin_amdgcn_mfma_f32_16x16x32_bf16(a, b, c, 0, 0, 0)

__device__ __forceinline__ u16 f2b(float f) {
    u32 u = __builtin_bit_cast(u32, f);
    u32 r = (u + 0x7fffu + ((u >> 16) & 1u)) >> 16;
    return (u16)r;
}
__device__ __forceinline__ float b2f(u16 h) {
    u32 u = ((u32)h) << 16;
    return __builtin_bit_cast(float, u);
}
__device__ __forceinline__ float sigm(float x) { return 1.0f / (1.0f + __expf(-x)); }
__device__ __forceinline__ float tanh_fast(float x) { return 1.0f - 2.0f / (__expf(2.0f * x) + 1.0f); }

// sc1 (MALL-coherent) accesses via agent-scope relaxed atomics. Used ONLY for
// h PUBLISHING (write-through so remote XCDs see it) and flags. h CONSUMPTION
// is plain cached loads: every h address is written exactly once per dispatch
// (write-once history), and L2s are invalidated at dispatch boundaries, so a
// cached line can never be stale. This cuts MALL read traffic 8x (16 WGs/XCD
// share each line through L2) -- the round-0/1 kernels were MALL-BW-bound on
// the 8 MB/step sc1 h broadcast (6.2 us/step at ~1.3 TB/s = measured 6.13).
__device__ __forceinline__ u32 aload32(const void* p) {
    return __hip_atomic_load((const u32*)p, __ATOMIC_RELAXED, __HIP_MEMORY_SCOPE_AGENT);
}
__device__ __forceinline__ void astore32(void* p, u32 v) {
    __hip_atomic_store((u32*)p, v, __ATOMIC_RELAXED, __HIP_MEMORY_SCOPE_AGENT);
}
__device__ __forceinline__ void astore64(void* p, u64 v) {
    __hip_atomic_store((u64*)p, v, __ATOMIC_RELAXED, __HIP_MEMORY_SCOPE_AGENT);
}

// ---------------------------------------------------------------------------
// Embedding gather + f32->bf16 cast, time-major output x[t*64+b][e]
__global__ __launch_bounds__(256) void embed_k(const int* __restrict__ enc,
                                               const float* __restrict__ emb,
                                               u16* __restrict__ xb) {
    int idx = (blockIdx.x * 256 + threadIdx.x) * 4;
    int row = idx >> 9;
    int e = idx & 511;
    int t = row >> 6, b = row & 63;
    int tok = enc[b * 256 + t];
    const float4 v = *(const float4*)(emb + (size_t)tok * 512 + e);
    u16x4 o;
    o.x = f2b(v.x); o.y = f2b(v.y); o.z = f2b(v.z); o.w = f2b(v.w);
    *(u16x4*)(xb + idx) = o;
}

// Mask words: maskw[t] bit b = (enc[b][t] != 0)
__global__ void mask_k(const int* __restrict__ enc, u64* __restrict__ mw) {
    int t = threadIdx.x;
    u64 m = 0;
#pragma unroll 8
    for (int b = 0; b < 64; ++b)
        if (enc[b * 256 + t] != 0) m |= (1ull << b);
    mw[t] = m;
}

// ---------------------------------------------------------------------------
// Cast f32 [K][N] -> bf16 transposed [N][K] via LDS tile
__global__ __launch_bounds__(256) void castT_k(const float* __restrict__ src,
                                               u16* __restrict__ dst, int K, int N) {
    __shared__ float tile[64][65];
    int n0 = blockIdx.x * 64, k0 = blockIdx.y * 64;
    int tid = threadIdx.x;
#pragma unroll
    for (int it = 0; it < 4; ++it) {
        int e = tid + it * 256;
        int kk = e >> 4;
        int nn = (e & 15) * 4;
        const float4 v = *(const float4*)(src + (size_t)(k0 + kk) * N + n0 + nn);
        tile[kk][nn] = v.x; tile[kk][nn + 1] = v.y;
        tile[kk][nn + 2] = v.z; tile[kk][nn + 3] = v.w;
    }
    __syncthreads();
#pragma unroll
    for (int it = 0; it < 2; ++it) {
        int e = tid + it * 256;
        int nn = e >> 3;
        int ks = (e & 7) * 8;
        u16x8 o;
#pragma unroll
        for (int j = 0; j < 8; ++j) o[j] = f2b(tile[ks + j][nn]);
        *(u16x8*)(dst + (size_t)(n0 + nn) * K + k0 + ks) = o;
    }
}

// ---------------------------------------------------------------------------
// bf16 MFMA GEMM: zxT[dir][t][col][b] = (A[16384][Ak] @ Bt[dir]^T + bias[dir]),
// output TRANSPOSED per timestep for the recurrence's vectorized reads.
__global__ __launch_bounds__(256) void gemm_bias_k(
    const u16* __restrict__ A, int Ak,
    const u16* __restrict__ BtF, const u16* __restrict__ BtB,
    const float* __restrict__ biasF, const float* __restrict__ biasB,
    u16* __restrict__ outF, u16* __restrict__ outB) {
    const int dir = blockIdx.z;
    const u16* __restrict__ Bt = dir ? BtB : BtF;
    const float* __restrict__ bias = dir ? biasB : biasF;
    u16* __restrict__ out = dir ? outB : outF;

    const int m0 = blockIdx.y * 128, n0 = blockIdx.x * 128;
    __shared__ __align__(16) u16 As[128 * 40];
    __shared__ __align__(16) u16 Bs[128 * 40];
    const int tid = threadIdx.x;
    const int lane = tid & 63, w = tid >> 6;
    const int l15 = lane & 15, quad = lane >> 4;
    const int rb = (w >> 1) * 64, cb = (w & 1) * 64;

    f32x4 acc[4][4];
#pragma unroll
    for (int i = 0; i < 4; ++i)
#pragma unroll
        for (int j = 0; j < 4; ++j) acc[i][j] = (f32x4){0.f, 0.f, 0.f, 0.f};

    const int nkt = Ak >> 5;
    for (int kt = 0; kt < nkt; ++kt) {
        __syncthreads();
#pragma unroll
        for (int it = 0; it < 2; ++it) {
            int s = tid + it * 256;
            int r = s >> 2, seg = s & 3;
            *(uint4*)&As[r * 40 + seg * 8] =
                *(const uint4*)&A[(size_t)(m0 + r) * Ak + kt * 32 + seg * 8];
            *(uint4*)&Bs[r * 40 + seg * 8] =
                *(const uint4*)&Bt[(size_t)(n0 + r) * Ak + kt * 32 + seg * 8];
        }
        __syncthreads();
        bf16x8 af[4], bfr[4];
#pragma unroll
        for (int i = 0; i < 4; ++i)
            af[i] = *(const bf16x8*)&As[(rb + i * 16 + l15) * 40 + quad * 8];
#pragma unroll
        for (int j = 0; j < 4; ++j)
            bfr[j] = *(const bf16x8*)&Bs[(cb + j * 16 + l15) * 40 + quad * 8];
#pragma unroll
        for (int i = 0; i < 4; ++i)
#pragma unroll
            for (int j = 0; j < 4; ++j) acc[i][j] = MFMA16(af[i], bfr[j], acc[i][j]);
    }
    // epilogue: add bias, store bf16 transposed: zxT[(t*2048 + col)*64 + b]
    // rows m..m+3 share t because m === 0 (mod 4) and 64 | t-boundary.
#pragma unroll
    for (int j = 0; j < 4; ++j) {
        int col = n0 + cb + j * 16 + l15;
        float bv = bias[col];
#pragma unroll
        for (int i = 0; i < 4; ++i) {
            int m = m0 + rb + i * 16 + quad * 4;
            int t = m >> 6, b0 = m & 63;
            u16x4 o;
#pragma unroll
            for (int r = 0; r < 4; ++r) o[r] = f2b(acc[i][j][r] + bv);
            *(u16x4*)&out[((size_t)t * 2048 + col) * 64 + b0] = o;
        }
    }
}

// ---------------------------------------------------------------------------
// Persistent bidirectional LSTM recurrence.
// 128 WGs: 0..63 fwd, 64..127 bwd. Each WG owns 8 units (32 gate-cols) with
// U-slices resident in registers.
// h exchange = WRITE-ONCE HISTORY hex[256][64][1024] bf16 ([t][b][dir*512+u]):
//   - producers publish h_t with sc1 (write-through, MALL-visible) 8B stores;
//     for layer 1 this history IS out1 (no separate output store at all).
//   - consumers read h_{t'} with PLAIN CACHED loads: each address is written
//     once per dispatch and L2s are invalidated at dispatch start, so lines
//     can't be stale; 16 WGs/XCD share each line via L2 (8x less MALL read).
// Barrier = per-WG flag (sc1, single writer) + single-poller wave 0 +
// __syncthreads broadcast (round-0 proven protocol; 4x fewer pollers than
// per-wave polling, which measurably congested the MALL).
__global__ __launch_bounds__(256, 1) void lstm_rec_k(
    const u16* __restrict__ zxF, const u16* __restrict__ zxB,  // [256][2048][64]
    const u16* __restrict__ UtF, const u16* __restrict__ UtB,  // [2048][512]
    const u64* __restrict__ maskw,
    u16* __restrict__ hex,     // [256][64][1024] write-once h history (=out1 for layer 1)
    u32* __restrict__ flgF, u32* __restrict__ flgB,            // each [64]
    float* __restrict__ out2,  // layer 2: d_out
    int layer) {
    const int wg = blockIdx.x;
    const int dir = wg >> 6;
    const int wgu = wg & 63;
    const u16* __restrict__ zx = dir ? zxB : zxF;
    const u16* __restrict__ Ut = dir ? UtB : UtF;
    u32* __restrict__ flg = dir ? flgB : flgF;

    const int tid = threadIdx.x;
    const int lane = tid & 63, w = tid >> 6;
    const int l15 = lane & 15, quad = lane >> 4;
    const bool hi = (lane & 8) != 0;
    const int gc_l = (l15 >> 3) * 512 + wgu * 8 + (l15 & 7);
    const int u = wgu * 8 + (lane & 7);
    const int brow = w * 16 + l15;
    const int b0 = w * 16 + quad * 4;  // batch base for acc rows

    // Preload U fragments: 2 N-tiles x 16 K-chunks (VGPR/AGPR-resident)
    bf16x8 bfr[2][16];
#pragma unroll
    for (int nt = 0; nt < 2; ++nt)
#pragma unroll
        for (int kt = 0; kt < 16; ++kt)
            bfr[nt][kt] = *(const bf16x8*)&Ut[(size_t)(nt * 1024 + gc_l) * 512 + kt * 32 + quad * 8];

    float hreg[4] = {0.f, 0.f, 0.f, 0.f};
    float creg[4] = {0.f, 0.f, 0.f, 0.f};

    // initial zx prefetch (t of step 0)
    int t0 = dir ? 255 : 0;
    u16x4 pz0 = *(const u16x4*)&zx[((size_t)t0 * 2048 + gc_l) * 64 + b0];
    u16x4 pz1 = *(const u16x4*)&zx[((size_t)t0 * 2048 + 1024 + gc_l) * 64 + b0];

    for (int s = 0; s < 256; ++s) {
        const int t = dir ? (255 - s) : s;
        const int tp = dir ? (t + 1) : (t - 1);  // history slot to consume (s>0)

        // gate: wait until all 64 WGs of this direction published step s.
        if (s) {
            if (tid < 64) {
                u32 v = aload32(&flg[tid]);
                while (__ballot(v < (u32)s)) v = aload32(&flg[tid]);
            }
            __syncthreads();
        }

        const u64 mw = maskw[t];  // hot 2KB table, hoisted early for slack

        f32x4 acc0, acc1;
#pragma unroll
        for (int r = 0; r < 4; ++r) { acc0[r] = b2f(pz0[r]); acc1[r] = b2f(pz1[r]); }

        if (s) {
            // h_{t'} slice: plain cached 16B loads (L2-shared within XCD)
            const u16* hbase = hex + ((size_t)tp * 64 + brow) * 1024 + dir * 512 + quad * 8;
            bf16x8 hfr[16];
#pragma unroll
            for (int kt = 0; kt < 16; ++kt) hfr[kt] = *(const bf16x8*)&hbase[kt * 32];
#pragma unroll
            for (int kt = 0; kt < 16; ++kt) {
                acc0 = MFMA16(hfr[kt], bfr[0][kt], acc0);
                acc1 = MFMA16(hfr[kt], bfr[1][kt], acc1);
            }
        }

#pragma unroll
        for (int r = 0; r < 4; ++r) {
            int b = b0 + r;
            float z0 = acc0[r], z1 = acc1[r];
            float p0 = __shfl_xor(z0, 8);
            float p1 = __shfl_xor(z1, 8);
            float iz = hi ? p0 : z0, fz = hi ? z0 : p0;
            float gz = hi ? p1 : z1, oz = hi ? z1 : p1;
            float i_ = sigm(iz), f_ = sigm(fz), g_ = tanh_fast(gz), o_ = sigm(oz);
            float cn = f_ * creg[r] + i_ * g_;
            float hv = o_ * tanh_fast(cn);
            if (!((mw >> b) & 1ull)) { cn = creg[r]; hv = hreg[r]; }
            creg[r] = cn; hreg[r] = hv;
            if (!hi) {
                u16 hb = f2b(hv);
                // pack (u..u+3) into u64; lane&3==0 stores 8B (u === 0 mod 4).
                // This sc1 store IS the out1 store for layer 1.
                u32 pair = (u32)hb | (((u32)(u16)__shfl_xor((int)(u32)hb, 1)) << 16);
                u64 q = (u64)pair | ((u64)(u32)__shfl_xor((int)pair, 2) << 32);
                if (!(lane & 3))
                    astore64(&hex[((size_t)t * 64 + b) * 1024 + dir * 512 + u], q);
            }
        }

        // drain h stores (compiler emits vmcnt(0) before s_barrier), publish
        __syncthreads();
        if (tid == 0) astore32(&flg[wgu], (u32)(s + 1));

        // post-publish: layer-2 output stores + next-step zx prefetch overlap
        // the next gate's poll.
        if (layer == 2 && !hi) {
#pragma unroll
            for (int r = 0; r < 4; ++r) {
                u32 h32 = __builtin_bit_cast(u32, hreg[r]);
                u32 ot = (u32)__shfl_xor((int)h32, 1);
                if (!(lane & 1)) {
                    u64 qq = (u64)h32 | ((u64)ot << 32);
                    *(u64*)&out2[(size_t)(b0 + r) * 262144 + (size_t)t * 1024 + dir * 512 + u] = qq;
                }
            }
            if (s == 255) {
#pragma unroll
                for (int r = 0; r < 4; ++r) {
                    int b = b0 + r;
                    out2[16777216 + b * 1024 + dir * 512 + u] = hreg[r];
                    out2[16777216 + 65536 + b * 1024 + dir * 512 + u] = creg[r];
                }
            }
        }
        {
            int tn = dir ? (s < 255 ? 254 - s : 0) : (s < 255 ? s + 1 : 255);
            pz0 = *(const u16x4*)&zx[((size_t)tn * 2048 + gc_l) * 64 + b0];
            pz1 = *(const u16x4*)&zx[((size_t)tn * 2048 + 1024 + gc_l) * 64 + b0];
        }
    }
}

// ---------------------------------------------------------------------------
extern "C" void kernel_launch(void* const* d_in, const int* in_sizes, int n_in,
                              void* d_out, int out_size, void* d_ws, size_t ws_size,
                              hipStream_t stream) {
    const int* enc = (const int*)d_in[0];
    const float* emb = (const float*)d_in[1];
    const float* W1f = (const float*)d_in[2];
    const float* U1f = (const float*)d_in[3];
    const float* b1f = (const float*)d_in[4];
    const float* W1b = (const float*)d_in[5];
    const float* U1b = (const float*)d_in[6];
    const float* b1b = (const float*)d_in[7];
    const float* W2f = (const float*)d_in[8];
    const float* U2f = (const float*)d_in[9];
    const float* b2f = (const float*)d_in[10];
    const float* W2b = (const float*)d_in[11];
    const float* U2b = (const float*)d_in[12];
    const float* b2b = (const float*)d_in[13];

    char* ws = (char*)d_ws;
    constexpr size_t ZXF = 0;                      // 67,108,864  bf16 [256][2048][64]
    constexpr size_t ZXB = 67108864;               // 67,108,864
    constexpr size_t XB = 134217728;               // 16,777,216  bf16 [16384][512]
    constexpr size_t OUT1 = 150994944;             // 33,554,432  bf16 [256][64][1024] = h history
    constexpr size_t WT = 184549376;               // 20,971,520 packed bf16 transposed weights
    constexpr size_t W1FT = WT + 0;
    constexpr size_t W1BT = WT + 2097152;
    constexpr size_t U1FT = WT + 4194304;
    constexpr size_t U1BT = WT + 6291456;
    constexpr size_t W2FT = WT + 8388608;
    constexpr size_t W2BT = WT + 12582912;
    constexpr size_t U2FT = WT + 16777216;
    constexpr size_t U2BT = WT + 18874368;
    constexpr size_t FLG = 205520896;              // 2 dirs x 64 u32 (reused per layer)
    constexpr size_t MASKW = FLG + 4096;           // 2048 bytes

    u16* zxF = (u16*)(ws + ZXF);
    u16* zxB = (u16*)(ws + ZXB);
    u16* xb = (u16*)(ws + XB);
    u16* out1 = (u16*)(ws + OUT1);
    u32* flgs = (u32*)(ws + FLG);
    u64* maskw = (u64*)(ws + MASKW);

    // zero flags (ws is poisoned 0xAA each launch)
    hipMemsetAsync(ws + FLG, 0, 4096, stream);

    embed_k<<<8192, 256, 0, stream>>>(enc, emb, xb);
    mask_k<<<1, 256, 0, stream>>>(enc, maskw);

    castT_k<<<dim3(32, 8), 256, 0, stream>>>(W1f, (u16*)(ws + W1FT), 512, 2048);
    castT_k<<<dim3(32, 8), 256, 0, stream>>>(W1b, (u16*)(ws + W1BT), 512, 2048);
    castT_k<<<dim3(32, 8), 256, 0, stream>>>(U1f, (u16*)(ws + U1FT), 512, 2048);
    castT_k<<<dim3(32, 8), 256, 0, stream>>>(U1b, (u16*)(ws + U1BT), 512, 2048);
    castT_k<<<dim3(32, 16), 256, 0, stream>>>(W2f, (u16*)(ws + W2FT), 1024, 2048);
    castT_k<<<dim3(32, 16), 256, 0, stream>>>(W2b, (u16*)(ws + W2BT), 1024, 2048);
    castT_k<<<dim3(32, 8), 256, 0, stream>>>(U2f, (u16*)(ws + U2FT), 512, 2048);
    castT_k<<<dim3(32, 8), 256, 0, stream>>>(U2b, (u16*)(ws + U2BT), 512, 2048);

    gemm_bias_k<<<dim3(16, 128, 2), 256, 0, stream>>>(
        xb, 512, (u16*)(ws + W1FT), (u16*)(ws + W1BT), b1f, b1b, zxF, zxB);
    // layer-1 recurrence: h history IS out1 (write-once, sc1-published)
    lstm_rec_k<<<128, 256, 0, stream>>>(
        zxF, zxB, (u16*)(ws + U1FT), (u16*)(ws + U1BT), maskw,
        out1, &flgs[0], &flgs[64], nullptr, 1);

    gemm_bias_k<<<dim3(16, 128, 2), 256, 0, stream>>>(
        out1, 1024, (u16*)(ws + W2FT), (u16*)(ws + W2BT), b2f, b2b, zxF, zxB);
    // re-zero flags for layer 2 (stream-ordered after rec1)
    hipMemsetAsync(ws + FLG, 0, 4096, stream);
    // layer-2 recurrence: reuse the (now dead) out1 region as its h history
    lstm_rec_k<<<128, 256, 0, stream>>>(
        zxF, zxB, (u16*)(ws + U2FT), (u16*)(ws + U2BT), maskw,
        out1, &flgs[0], &flgs[64], (float*)d_out, 2);
}

// Round 3
// 2857.016 us; speedup vs baseline: 1.6959x; 1.0928x over previous
//
#include <hip/hip_runtime.h>

typedef unsigned short u16;
typedef unsigned int u32;
typedef unsigned long long u64;
typedef __attribute__((ext_vector_type(8))) short bf16x8;
typedef __attribute__((ext_vector_type(4))) float f32x4;
typedef __attribute__((ext_vector_type(8))) unsigned short u16x8;
typedef __attribute__((ext_vector_type(4))) unsigned short u16x4;

#define MFMA16(a, b, c) __builtin_amdgcn_mfma_f32_16x16x32_bf16(a, b, c, 0, 0, 0)

__device__ __forceinline__ u16 f2b(float f) {
    u32 u = __builtin_bit_cast(u32, f);
    u32 r = (u + 0x7fffu + ((u >> 16) & 1u)) >> 16;
    return (u16)r;
}
__device__ __forceinline__ float b2f(u16 h) {
    u32 u = ((u32)h) << 16;
    return __builtin_bit_cast(float, u);
}
__device__ __forceinline__ float sigm(float x) { return 1.0f / (1.0f + __expf(-x)); }
__device__ __forceinline__ float tanh_fast(float x) { return 1.0f - 2.0f / (__expf(2.0f * x) + 1.0f); }

// sc1 (MALL-coherent) accesses via agent-scope relaxed atomics: h PUBLISHING
// (write-through so remote XCDs see it) and flags only. h CONSUMPTION is
// plain cached loads (write-once history + dispatch-boundary L2 invalidation
// => never stale). Proven in round 2.
__device__ __forceinline__ u32 aload32(const void* p) {
    return __hip_atomic_load((const u32*)p, __ATOMIC_RELAXED, __HIP_MEMORY_SCOPE_AGENT);
}
__device__ __forceinline__ void astore32(void* p, u32 v) {
    __hip_atomic_store((u32*)p, v, __ATOMIC_RELAXED, __HIP_MEMORY_SCOPE_AGENT);
}
__device__ __forceinline__ void astore64(void* p, u64 v) {
    __hip_atomic_store((u64*)p, v, __ATOMIC_RELAXED, __HIP_MEMORY_SCOPE_AGENT);
}

// ---------------------------------------------------------------------------
// Embedding gather + f32->bf16 cast, time-major output x[t*64+b][e]
__global__ __launch_bounds__(256) void embed_k(const int* __restrict__ enc,
                                               const float* __restrict__ emb,
                                               u16* __restrict__ xb) {
    int idx = (blockIdx.x * 256 + threadIdx.x) * 4;
    int row = idx >> 9;
    int e = idx & 511;
    int t = row >> 6, b = row & 63;
    int tok = enc[b * 256 + t];
    const float4 v = *(const float4*)(emb + (size_t)tok * 512 + e);
    u16x4 o;
    o.x = f2b(v.x); o.y = f2b(v.y); o.z = f2b(v.z); o.w = f2b(v.w);
    *(u16x4*)(xb + idx) = o;
}

// Mask words: maskw[t] bit b = (enc[b][t] != 0)
__global__ void mask_k(const int* __restrict__ enc, u64* __restrict__ mw) {
    int t = threadIdx.x;
    u64 m = 0;
#pragma unroll 8
    for (int b = 0; b < 64; ++b)
        if (enc[b * 256 + t] != 0) m |= (1ull << b);
    mw[t] = m;
}

// ---------------------------------------------------------------------------
// Cast f32 [K][N] -> bf16 transposed [N][K] via LDS tile
__global__ __launch_bounds__(256) void castT_k(const float* __restrict__ src,
                                               u16* __restrict__ dst, int K, int N) {
    __shared__ float tile[64][65];
    int n0 = blockIdx.x * 64, k0 = blockIdx.y * 64;
    int tid = threadIdx.x;
#pragma unroll
    for (int it = 0; it < 4; ++it) {
        int e = tid + it * 256;
        int kk = e >> 4;
        int nn = (e & 15) * 4;
        const float4 v = *(const float4*)(src + (size_t)(k0 + kk) * N + n0 + nn);
        tile[kk][nn] = v.x; tile[kk][nn + 1] = v.y;
        tile[kk][nn + 2] = v.z; tile[kk][nn + 3] = v.w;
    }
    __syncthreads();
#pragma unroll
    for (int it = 0; it < 2; ++it) {
        int e = tid + it * 256;
        int nn = e >> 3;
        int ks = (e & 7) * 8;
        u16x8 o;
#pragma unroll
        for (int j = 0; j < 8; ++j) o[j] = f2b(tile[ks + j][nn]);
        *(u16x8*)(dst + (size_t)(n0 + nn) * K + k0 + ks) = o;
    }
}

// ---------------------------------------------------------------------------
// bf16 MFMA GEMM: zx = A[16384][Ak] @ Bt^T + bias, output laid out as
// zx[t][grp][2048 cols][16 b] so each 16-batch group's slice is
// cache-line-contiguous (no cross-group line sharing in the recurrence).
__global__ __launch_bounds__(256) void gemm_bias_k(
    const u16* __restrict__ A, int Ak,
    const u16* __restrict__ BtF, const u16* __restrict__ BtB,
    const float* __restrict__ biasF, const float* __restrict__ biasB,
    u16* __restrict__ outF, u16* __restrict__ outB) {
    const int dir = blockIdx.z;
    const u16* __restrict__ Bt = dir ? BtB : BtF;
    const float* __restrict__ bias = dir ? biasB : biasF;
    u16* __restrict__ out = dir ? outB : outF;

    const int m0 = blockIdx.y * 128, n0 = blockIdx.x * 128;
    __shared__ __align__(16) u16 As[128 * 40];
    __shared__ __align__(16) u16 Bs[128 * 40];
    const int tid = threadIdx.x;
    const int lane = tid & 63, w = tid >> 6;
    const int l15 = lane & 15, quad = lane >> 4;
    const int rb = (w >> 1) * 64, cb = (w & 1) * 64;

    f32x4 acc[4][4];
#pragma unroll
    for (int i = 0; i < 4; ++i)
#pragma unroll
        for (int j = 0; j < 4; ++j) acc[i][j] = (f32x4){0.f, 0.f, 0.f, 0.f};

    const int nkt = Ak >> 5;
    for (int kt = 0; kt < nkt; ++kt) {
        __syncthreads();
#pragma unroll
        for (int it = 0; it < 2; ++it) {
            int s = tid + it * 256;
            int r = s >> 2, seg = s & 3;
            *(uint4*)&As[r * 40 + seg * 8] =
                *(const uint4*)&A[(size_t)(m0 + r) * Ak + kt * 32 + seg * 8];
            *(uint4*)&Bs[r * 40 + seg * 8] =
                *(const uint4*)&Bt[(size_t)(n0 + r) * Ak + kt * 32 + seg * 8];
        }
        __syncthreads();
        bf16x8 af[4], bfr[4];
#pragma unroll
        for (int i = 0; i < 4; ++i)
            af[i] = *(const bf16x8*)&As[(rb + i * 16 + l15) * 40 + quad * 8];
#pragma unroll
        for (int j = 0; j < 4; ++j)
            bfr[j] = *(const bf16x8*)&Bs[(cb + j * 16 + l15) * 40 + quad * 8];
#pragma unroll
        for (int i = 0; i < 4; ++i)
#pragma unroll
            for (int j = 0; j < 4; ++j) acc[i][j] = MFMA16(af[i], bfr[j], acc[i][j]);
    }
    // epilogue: add bias, store bf16: zx[((t*4+grp)*2048 + col)*16 + bi]
#pragma unroll
    for (int j = 0; j < 4; ++j) {
        int col = n0 + cb + j * 16 + l15;
        float bv = bias[col];
#pragma unroll
        for (int i = 0; i < 4; ++i) {
            int m = m0 + rb + i * 16 + quad * 4;
            int t = m >> 6, b0 = m & 63;
            int grp = b0 >> 4, bi = b0 & 15;
            u16x4 o;
#pragma unroll
            for (int r = 0; r < 4; ++r) o[r] = f2b(acc[i][j][r] + bv);
            *(u16x4*)&out[(((size_t)t * 4 + grp) * 2048 + col) * 16 + bi] = o;
        }
    }
}

// ---------------------------------------------------------------------------
// Persistent bidirectional LSTM recurrence, NARROW-SCOPE barriers.
// The recurrence is batch-diagonal: h_t[b] depends only on h_{t-1}[b]. So the
// per-step all-to-all (through U) is confined to a batch group. Partition:
// 2 dirs x 4 groups of 16 batches x 16 WGs (each owns 32 units = 128 gate
// cols). 8 fully independent 16-WG systems instead of 2 coupled 64-WG ones:
// flag block per system = one cache line, h slice per step = 16 KB, and
// straggler jitter no longer couples globally.
// Protocol per step (identical to round 2, narrower scope): poll 16 flags ->
// __syncthreads -> cached h loads -> MFMA -> gates -> sc1 h stores ->
// __syncthreads (drains vmcnt) -> flag=s+1 -> out2 stores + zx prefetch.
// h history hex[256][64][1024] bf16 doubles as out1 for layer 1.
__global__ __launch_bounds__(256, 1) void lstm_rec_k(
    const u16* __restrict__ zxF, const u16* __restrict__ zxB,  // [256][4][2048][16]
    const u16* __restrict__ UtF, const u16* __restrict__ UtB,  // [2048][512]
    const u64* __restrict__ maskw,
    u16* __restrict__ hex,     // [256][64][1024] write-once h history (=out1 for layer 1)
    u32* __restrict__ flgs,    // [2][4][32] u32, 128B-aligned blocks per system
    float* __restrict__ out2,  // layer 2: d_out
    int layer) {
    const int wg = blockIdx.x;
    const int dir = wg >> 6;
    const int grp = (wg >> 4) & 3;   // batch group (16 rows)
    const int wu = wg & 15;          // unit block (32 units)
    const u16* __restrict__ zx = dir ? zxB : zxF;
    const u16* __restrict__ Ut = dir ? UtB : UtF;
    u32* __restrict__ flg = flgs + (dir * 4 + grp) * 32;

    const int tid = threadIdx.x;
    const int lane = tid & 63, w = tid >> 6;
    const int l15 = lane & 15, quad = lane >> 4;
    const bool hi = (lane & 8) != 0;
    const int gc_l = (l15 >> 3) * 512 + wu * 32 + w * 8 + (l15 & 7);
    const int u = wu * 32 + w * 8 + (lane & 7);
    const int brow = grp * 16 + l15;        // h row this lane reads
    const int b0 = grp * 16 + quad * 4;     // batch base for acc rows
    const int bi0 = quad * 4;               // batch-in-group base for zx reads

    // Preload U fragments: 2 N-tiles x 16 K-chunks (VGPR/AGPR-resident)
    bf16x8 bfr[2][16];
#pragma unroll
    for (int nt = 0; nt < 2; ++nt)
#pragma unroll
        for (int kt = 0; kt < 16; ++kt)
            bfr[nt][kt] = *(const bf16x8*)&Ut[(size_t)(nt * 1024 + gc_l) * 512 + kt * 32 + quad * 8];

    float hreg[4] = {0.f, 0.f, 0.f, 0.f};
    float creg[4] = {0.f, 0.f, 0.f, 0.f};

    // initial zx prefetch (t of step 0)
    int t0 = dir ? 255 : 0;
    u16x4 pz0 = *(const u16x4*)&zx[(((size_t)t0 * 4 + grp) * 2048 + gc_l) * 16 + bi0];
    u16x4 pz1 = *(const u16x4*)&zx[(((size_t)t0 * 4 + grp) * 2048 + 1024 + gc_l) * 16 + bi0];

    for (int s = 0; s < 256; ++s) {
        const int t = dir ? (255 - s) : s;
        const int tp = dir ? (t + 1) : (t - 1);  // history slot to consume (s>0)

        // gate: wait until all 16 WGs of this (dir,grp) published step s.
        if (s) {
            if (tid < 16) {
                u32 v = aload32(&flg[tid]);
                while (__ballot(v < (u32)s)) v = aload32(&flg[tid]);
            }
            __syncthreads();
        }

        const u64 mw = maskw[t];

        f32x4 acc0, acc1;
#pragma unroll
        for (int r = 0; r < 4; ++r) { acc0[r] = b2f(pz0[r]); acc1[r] = b2f(pz1[r]); }

        if (s) {
            // h_{t'} slice for this group's 16 rows: plain cached 16B loads
            const u16* hbase = hex + ((size_t)tp * 64 + brow) * 1024 + dir * 512 + quad * 8;
            bf16x8 hfr[16];
#pragma unroll
            for (int kt = 0; kt < 16; ++kt) hfr[kt] = *(const bf16x8*)&hbase[kt * 32];
#pragma unroll
            for (int kt = 0; kt < 16; ++kt) {
                acc0 = MFMA16(hfr[kt], bfr[0][kt], acc0);
                acc1 = MFMA16(hfr[kt], bfr[1][kt], acc1);
            }
        }

#pragma unroll
        for (int r = 0; r < 4; ++r) {
            int b = b0 + r;
            float z0 = acc0[r], z1 = acc1[r];
            float p0 = __shfl_xor(z0, 8);
            float p1 = __shfl_xor(z1, 8);
            float iz = hi ? p0 : z0, fz = hi ? z0 : p0;
            float gz = hi ? p1 : z1, oz = hi ? z1 : p1;
            float i_ = sigm(iz), f_ = sigm(fz), g_ = tanh_fast(gz), o_ = sigm(oz);
            float cn = f_ * creg[r] + i_ * g_;
            float hv = o_ * tanh_fast(cn);
            if (!((mw >> b) & 1ull)) { cn = creg[r]; hv = hreg[r]; }
            creg[r] = cn; hreg[r] = hv;
            if (!hi) {
                u16 hb = f2b(hv);
                // pack (u..u+3) into u64; lane&3==0 stores 8B (u === 0 mod 4).
                // This sc1 store IS the out1 store for layer 1.
                u32 pair = (u32)hb | (((u32)(u16)__shfl_xor((int)(u32)hb, 1)) << 16);
                u64 q = (u64)pair | ((u64)(u32)__shfl_xor((int)pair, 2) << 32);
                if (!(lane & 3))
                    astore64(&hex[((size_t)t * 64 + b) * 1024 + dir * 512 + u], q);
            }
        }

        // drain h stores (compiler emits vmcnt(0) before s_barrier), publish
        __syncthreads();
        if (tid == 0) astore32(&flg[wu], (u32)(s + 1));

        // post-publish: layer-2 output stores + next-step zx prefetch overlap
        // the next gate's poll.
        if (layer == 2 && !hi) {
#pragma unroll
            for (int r = 0; r < 4; ++r) {
                u32 h32 = __builtin_bit_cast(u32, hreg[r]);
                u32 ot = (u32)__shfl_xor((int)h32, 1);
                if (!(lane & 1)) {
                    u64 qq = (u64)h32 | ((u64)ot << 32);
                    *(u64*)&out2[(size_t)(b0 + r) * 262144 + (size_t)t * 1024 + dir * 512 + u] = qq;
                }
            }
            if (s == 255) {
#pragma unroll
                for (int r = 0; r < 4; ++r) {
                    int b = b0 + r;
                    out2[16777216 + b * 1024 + dir * 512 + u] = hreg[r];
                    out2[16777216 + 65536 + b * 1024 + dir * 512 + u] = creg[r];
                }
            }
        }
        {
            int tn = dir ? (s < 255 ? 254 - s : 0) : (s < 255 ? s + 1 : 255);
            pz0 = *(const u16x4*)&zx[(((size_t)tn * 4 + grp) * 2048 + gc_l) * 16 + bi0];
            pz1 = *(const u16x4*)&zx[(((size_t)tn * 4 + grp) * 2048 + 1024 + gc_l) * 16 + bi0];
        }
    }
}

// ---------------------------------------------------------------------------
extern "C" void kernel_launch(void* const* d_in, const int* in_sizes, int n_in,
                              void* d_out, int out_size, void* d_ws, size_t ws_size,
                              hipStream_t stream) {
    const int* enc = (const int*)d_in[0];
    const float* emb = (const float*)d_in[1];
    const float* W1f = (const float*)d_in[2];
    const float* U1f = (const float*)d_in[3];
    const float* b1f = (const float*)d_in[4];
    const float* W1b = (const float*)d_in[5];
    const float* U1b = (const float*)d_in[6];
    const float* b1b = (const float*)d_in[7];
    const float* W2f = (const float*)d_in[8];
    const float* U2f = (const float*)d_in[9];
    const float* b2f = (const float*)d_in[10];
    const float* W2b = (const float*)d_in[11];
    const float* U2b = (const float*)d_in[12];
    const float* b2b = (const float*)d_in[13];

    char* ws = (char*)d_ws;
    constexpr size_t ZXF = 0;                      // 67,108,864  bf16 [256][4][2048][16]
    constexpr size_t ZXB = 67108864;               // 67,108,864
    constexpr size_t XB = 134217728;               // 16,777,216  bf16 [16384][512]
    constexpr size_t OUT1 = 150994944;             // 33,554,432  bf16 [256][64][1024] = h history
    constexpr size_t WT = 184549376;               // 20,971,520 packed bf16 transposed weights
    constexpr size_t W1FT = WT + 0;
    constexpr size_t W1BT = WT + 2097152;
    constexpr size_t U1FT = WT + 4194304;
    constexpr size_t U1BT = WT + 6291456;
    constexpr size_t W2FT = WT + 8388608;
    constexpr size_t W2BT = WT + 12582912;
    constexpr size_t U2FT = WT + 16777216;
    constexpr size_t U2BT = WT + 18874368;
    constexpr size_t FLG = 205520896;              // [2][4][32] u32 (reused per layer)
    constexpr size_t MASKW = FLG + 4096;           // 2048 bytes

    u16* zxF = (u16*)(ws + ZXF);
    u16* zxB = (u16*)(ws + ZXB);
    u16* xb = (u16*)(ws + XB);
    u16* out1 = (u16*)(ws + OUT1);
    u32* flgs = (u32*)(ws + FLG);
    u64* maskw = (u64*)(ws + MASKW);

    // zero flags (ws is poisoned 0xAA each launch)
    hipMemsetAsync(ws + FLG, 0, 4096, stream);

    embed_k<<<8192, 256, 0, stream>>>(enc, emb, xb);
    mask_k<<<1, 256, 0, stream>>>(enc, maskw);

    castT_k<<<dim3(32, 8), 256, 0, stream>>>(W1f, (u16*)(ws + W1FT), 512, 2048);
    castT_k<<<dim3(32, 8), 256, 0, stream>>>(W1b, (u16*)(ws + W1BT), 512, 2048);
    castT_k<<<dim3(32, 8), 256, 0, stream>>>(U1f, (u16*)(ws + U1FT), 512, 2048);
    castT_k<<<dim3(32, 8), 256, 0, stream>>>(U1b, (u16*)(ws + U1BT), 512, 2048);
    castT_k<<<dim3(32, 16), 256, 0, stream>>>(W2f, (u16*)(ws + W2FT), 1024, 2048);
    castT_k<<<dim3(32, 16), 256, 0, stream>>>(W2b, (u16*)(ws + W2BT), 1024, 2048);
    castT_k<<<dim3(32, 8), 256, 0, stream>>>(U2f, (u16*)(ws + U2FT), 512, 2048);
    castT_k<<<dim3(32, 8), 256, 0, stream>>>(U2b, (u16*)(ws + U2BT), 512, 2048);

    gemm_bias_k<<<dim3(16, 128, 2), 256, 0, stream>>>(
        xb, 512, (u16*)(ws + W1FT), (u16*)(ws + W1BT), b1f, b1b, zxF, zxB);
    // layer-1 recurrence: h history IS out1 (write-once, sc1-published)
    lstm_rec_k<<<128, 256, 0, stream>>>(
        zxF, zxB, (u16*)(ws + U1FT), (u16*)(ws + U1BT), maskw,
        out1, flgs, nullptr, 1);

    gemm_bias_k<<<dim3(16, 128, 2), 256, 0, stream>>>(
        out1, 1024, (u16*)(ws + W2FT), (u16*)(ws + W2BT), b2f, b2b, zxF, zxB);
    // re-zero flags for layer 2 (stream-ordered after rec1)
    hipMemsetAsync(ws + FLG, 0, 4096, stream);
    // layer-2 recurrence: reuse the (now dead) out1 region as its h history
    lstm_rec_k<<<128, 256, 0, stream>>>(
        zxF, zxB, (u16*)(ws + U2FT), (u16*)(ws + U2BT), maskw,
        out1, flgs, (float*)d_out, 2);
}